// Round 6
// baseline (213.276 us; speedup 1.0000x reference)
//
#include <hip/hip_runtime.h>
#include <hip/hip_bf16.h>

#define NN 100000
#define NE 1600000
#define INF 256
#define OUTF 128
#define NHALF 50000
#define NBK ((NN + 127) / 128)           // 782 buckets of 128 nodes
#define CHUNK 4096
#define NBA ((NE + CHUNK - 1) / CHUNK)   // 391 chunks

typedef __attribute__((ext_vector_type(8))) short short8;
typedef __attribute__((ext_vector_type(4))) float f32x4;
typedef __attribute__((ext_vector_type(4))) uint u32x4;

static __device__ __forceinline__ short f2bf(float f) {
    __hip_bfloat16 h = __float2bfloat16(f);
    return *reinterpret_cast<short*>(&h);
}

// ---------------------------------------------------------------------------
// Setup: block 0: wsv = W@a_src, wdv = W@a_dst;
// blocks 1..8: swizzled bf16 B fragments of W_em.
// Bsw layout: [kt(8)][ct(8)][lane(64)][j(8)]:
//   bf16(Wem[kt*32 + (lane>>4)*8 + j][ct*16 + (lane&15)])
// ---------------------------------------------------------------------------
__global__ void k_setup(const float* __restrict__ W, const float* __restrict__ a,
                        const float* __restrict__ Wem,
                        float* __restrict__ wsv, float* __restrict__ wdv,
                        ushort* __restrict__ Bsw) {
    const int b = blockIdx.x, t = threadIdx.x;
    if (b == 0) {
        const float* Wr = W + (size_t)t * OUTF;
        float sa = 0.f, sb = 0.f;
        #pragma unroll 8
        for (int k = 0; k < OUTF; ++k) {
            float w = Wr[k];
            sa += w * a[k];
            sb += w * a[OUTF + k];
        }
        wsv[t] = sa;
        wdv[t] = sb;
    } else {
        const int kt = b - 1;
        for (int idx = t; idx < 4096; idx += 256) {
            const int ct = idx >> 9;
            const int lane = (idx >> 3) & 63;
            const int j = idx & 7;
            const int k = kt * 32 + (lane >> 4) * 8 + j;
            const int c = ct * 16 + (lane & 15);
            Bsw[((size_t)(kt * 8 + ct) * 64 + lane) * 8 + j] =
                (ushort)f2bf(Wem[(size_t)k * OUTF + c]);
        }
    }
}

// ---------------------------------------------------------------------------
// MFMA matmul: hem(bf16) = x @ W_em; fused f32 s1 = x.ws, s2 = x.wd.
// C/D: col = lane&15, row = (lane>>4)*4 + reg   [m89/m91 verified mapping]
// hem stored as 8 XCD-L2-resident TILES of 64-byte rows:
//   tile (fs in 0..3, dh in 0..1) = [(fs*2+dh)*NHALF + (row - dh*NHALF)] * 32
//   holds features fs*32..fs*32+31 for rows in half dh. Tile = 3.2 MB.
//   64 B rows = one full L2 granule consumed per edge-touch (round-4 model).
// ---------------------------------------------------------------------------
__global__ __launch_bounds__(256) void k_mm(
    const float* __restrict__ x, const ushort* __restrict__ Bsw,
    const float* __restrict__ wsv, const float* __restrict__ wdv,
    float* __restrict__ s1, float* __restrict__ s2, ushort* __restrict__ hem) {
    const int t = threadIdx.x;
    const int w = t >> 6, lane = t & 63;
    const int br = blockIdx.x * 64 + w * 16;
    const int r0 = lane & 15, kq = lane >> 4;
    const int row = br + r0;
    const int rowc = (row < NN) ? row : NN - 1;
    const float* xp = x + (size_t)rowc * INF + kq * 8;
    const short8* bp = reinterpret_cast<const short8*>(Bsw);

    f32x4 acc[8];
    #pragma unroll
    for (int ct = 0; ct < 8; ++ct) acc[ct] = (f32x4){0.f, 0.f, 0.f, 0.f};
    float sa = 0.f, sb = 0.f;

    #pragma unroll
    for (int kt = 0; kt < 8; ++kt) {
        const float4 a0 = *reinterpret_cast<const float4*>(xp + kt * 32);
        const float4 a1 = *reinterpret_cast<const float4*>(xp + kt * 32 + 4);
        const float4 w0 = *reinterpret_cast<const float4*>(wsv + kt * 32 + kq * 8);
        const float4 w1 = *reinterpret_cast<const float4*>(wsv + kt * 32 + kq * 8 + 4);
        const float4 u0 = *reinterpret_cast<const float4*>(wdv + kt * 32 + kq * 8);
        const float4 u1 = *reinterpret_cast<const float4*>(wdv + kt * 32 + kq * 8 + 4);
        sa += a0.x * w0.x + a0.y * w0.y + a0.z * w0.z + a0.w * w0.w
            + a1.x * w1.x + a1.y * w1.y + a1.z * w1.z + a1.w * w1.w;
        sb += a0.x * u0.x + a0.y * u0.y + a0.z * u0.z + a0.w * u0.w
            + a1.x * u1.x + a1.y * u1.y + a1.z * u1.z + a1.w * u1.w;
        short8 af;
        af[0] = f2bf(a0.x); af[1] = f2bf(a0.y); af[2] = f2bf(a0.z); af[3] = f2bf(a0.w);
        af[4] = f2bf(a1.x); af[5] = f2bf(a1.y); af[6] = f2bf(a1.z); af[7] = f2bf(a1.w);
        #pragma unroll
        for (int ct = 0; ct < 8; ++ct) {
            const short8 bf = bp[(size_t)(kt * 8 + ct) * 64 + lane];
            acc[ct] = __builtin_amdgcn_mfma_f32_16x16x32_bf16(af, bf, acc[ct], 0, 0, 0);
        }
    }

    sa += __shfl_xor(sa, 16); sa += __shfl_xor(sa, 32);
    sb += __shfl_xor(sb, 16); sb += __shfl_xor(sb, 32);
    if (kq == 0 && row < NN) { s1[row] = sa; s2[row] = sb; }

    #pragma unroll
    for (int ct = 0; ct < 8; ++ct) {
        const int fs = ct >> 1;
        const int cw = (ct & 1) * 16 + r0;
        #pragma unroll
        for (int i = 0; i < 4; ++i) {
            const int rr = br + kq * 4 + i;
            if (rr < NN) {
                const int dh = (rr >= NHALF) ? 1 : 0;
                const int np = rr - dh * NHALF;
                hem[((size_t)(fs * 2 + dh) * NHALF + np) * 32 + cw] =
                    (ushort)f2bf(acc[ct][i]);
            }
        }
    }
}

// ---------------------------------------------------------------------------
// Per-chunk per-bucket counts (LDS only, no global atomics).
// ---------------------------------------------------------------------------
__global__ __launch_bounds__(256) void k_cnt(
    const int* __restrict__ src, int* __restrict__ cntA) {
    __shared__ int cnt[NBK];
    const int t = threadIdx.x;
    const int c = blockIdx.x;
    const int e0 = c * CHUNK;
    for (int i = t; i < NBK; i += 256) cnt[i] = 0;
    __syncthreads();
    for (int i = t; i < CHUNK; i += 256) {
        const int e = e0 + i;
        if (e < NE) atomicAdd(&cnt[src[e] >> 7], 1);
    }
    __syncthreads();
    for (int i = t; i < NBK; i += 256) cntA[(size_t)c * NBK + i] = cnt[i];
}

// ---------------------------------------------------------------------------
// Per-bucket scan over chunks: baseA[c][b] = exclusive sum, bsumB[b] = total.
// ---------------------------------------------------------------------------
__global__ __launch_bounds__(512) void k_cscan(
    const int* __restrict__ cntA, int* __restrict__ baseA,
    int* __restrict__ bsumB) {
    __shared__ int sm[512];
    const int b = blockIdx.x;
    const int t = threadIdx.x;
    const int v = (t < NBA) ? cntA[(size_t)t * NBK + b] : 0;
    sm[t] = v;
    __syncthreads();
    for (int off = 1; off < 512; off <<= 1) {
        const int add = (t >= off) ? sm[t - off] : 0;
        __syncthreads();
        sm[t] += add;
        __syncthreads();
    }
    if (t < NBA) baseA[(size_t)t * NBK + b] = sm[t] - v;
    if (t == 511) bsumB[b] = sm[511];
}

// ---------------------------------------------------------------------------
// Bucket exclusive scan (1 block, 1024 threads, NBK=782) + sentinels.
// ---------------------------------------------------------------------------
__global__ __launch_bounds__(1024) void k_bbase(
    const int* __restrict__ bsumB, int* __restrict__ bbase,
    int* __restrict__ offs2) {
    __shared__ int sm[1024];
    const int t = threadIdx.x;
    const int v = (t < NBK) ? bsumB[t] : 0;
    sm[t] = v;
    __syncthreads();
    for (int off = 1; off < 1024; off <<= 1) {
        const int add = (t >= off) ? sm[t - off] : 0;
        __syncthreads();
        sm[t] += add;
        __syncthreads();
    }
    if (t < NBK) bbase[t] = sm[t] - v;
    if (t == 0) { bbase[NBK] = NE; offs2[2 * NN] = NE; }
}

// ---------------------------------------------------------------------------
// Pass A (fused edge_e): single-pass deterministic scatter into bucket runs.
// ee = s1[s]+s2[d] -> edge_e output; v = exp(sigmoid(ee)) in (1,e) quantized
// to vq = round((v-1)*16384) (abs err <= 3e-5). NO global atomics.
// ebA record: { (dst<<7) | (src&127), vq }
// ---------------------------------------------------------------------------
__global__ __launch_bounds__(256) void k_binA(
    const int* __restrict__ src, const int* __restrict__ dst,
    const float* __restrict__ s1, const float* __restrict__ s2,
    float* __restrict__ ee_out, const int* __restrict__ bbase,
    const int* __restrict__ baseA, int2* __restrict__ ebA) {
    __shared__ int base[NBK];
    __shared__ int cnt[NBK];
    const int t = threadIdx.x;
    const int c = blockIdx.x;
    const int e0 = c * CHUNK;
    for (int i = t; i < NBK; i += 256) {
        base[i] = bbase[i] + baseA[(size_t)c * NBK + i];
        cnt[i] = 0;
    }
    __syncthreads();
    for (int i = t; i < CHUNK; i += 256) {
        const int e = e0 + i;
        if (e < NE) {
            const int s = src[e], d = dst[e];
            const float ee = s1[s] + s2[d];
            ee_out[e] = ee;
            const float ob = 1.f / (1.f + __expf(-ee));
            const float v = __expf(ob);                   // in (1, e)
            int vq = (int)((v - 1.f) * 16384.f + 0.5f);   // <= 28147
            vq = (vq > 32767) ? 32767 : vq;
            const int bk = s >> 7;
            const int r = atomicAdd(&cnt[bk], 1);
            ebA[base[bk] + r] = make_int2((d << 7) | (s & 127), vq);
        }
    }
}

// ---------------------------------------------------------------------------
// Pass B: one block per bucket. 256 virtual bins = (node-in-bucket, dst-half).
// Pass 1: LDS count per vid + vq-sum per node; 256-scan -> CSR offs2[2n+dh]
// and folded 1/denominator. Pass 2: scatter 4-byte records:
//   rec = (dp<<15) | attq,  dp = dst - dh*50000 (<2^16), attq in [0,32767]
//   attq = round((16384+vq) * 32767 / (16384*cnt + vqsum))  (exact ints)
// ---------------------------------------------------------------------------
__global__ __launch_bounds__(256) void k_sortB(
    const int* __restrict__ bbase, const int2* __restrict__ ebA,
    uint* __restrict__ ebB, int* __restrict__ offs2) {
    __shared__ int cnt[256];
    __shared__ int sum[128];
    __shared__ int sm[256];
    __shared__ int cur[256];
    __shared__ float fsl[128];
    const int b = blockIdx.x, t = threadIdx.x;
    const int n0 = b << 7;
    const int lo = bbase[b];
    const int hi = bbase[b + 1];
    cnt[t] = 0;
    if (t < 128) sum[t] = 0;
    __syncthreads();
    for (int i = lo + t; i < hi; i += 256) {
        const int2 r = ebA[i];
        const int sidx = r.x & 127;
        const uint d = ((unsigned)r.x) >> 7;
        const int vid = (sidx << 1) | (d >= (uint)NHALF ? 1 : 0);
        atomicAdd(&cnt[vid], 1);
        atomicAdd(&sum[sidx], r.y);
    }
    __syncthreads();
    const int v = cnt[t];
    sm[t] = v;
    __syncthreads();
    for (int off = 1; off < 256; off <<= 1) {
        const int add = (t >= off) ? sm[t - off] : 0;
        __syncthreads();
        sm[t] += add;
        __syncthreads();
    }
    const int excl = sm[t] - v;
    cur[t] = excl;
    if (n0 + (t >> 1) < NN) offs2[n0 * 2 + t] = lo + excl;
    if (t < 128) {
        const int c = cnt[2 * t] + cnt[2 * t + 1];
        fsl[t] = (c > 0) ? 32767.f / (float)(c * 16384 + sum[t]) : 0.f;
    }
    __syncthreads();
    for (int i = lo + t; i < hi; i += 256) {
        const int2 r = ebA[i];
        const int sidx = r.x & 127;
        const uint d = ((unsigned)r.x) >> 7;
        const int dh = (d >= (uint)NHALF) ? 1 : 0;
        const uint dp = d - (uint)(dh * NHALF);
        const float att = (float)(16384 + r.y) * fsl[sidx];
        int attq = (int)(att + 0.5f);
        attq = (attq > 32767) ? 32767 : attq;
        const int p = atomicAdd(&cur[(sidx << 1) | dh], 1);
        ebB[lo + p] = (dp << 15) | (uint)attq;
    }
}

// ---------------------------------------------------------------------------
// Aggregation, 2D-tiled: tile (fs = tile8>>1, dh = launch arg).
// tile8 = blockIdx&7 -> XCD-pinned; each fs held by 2 XCDs which split the
// node space (nb = (blockIdx>>3)*2 + (tile8&1)). Per tile the resident hem
// block is 3.2 MB of 64 B rows -> each edge-touch consumes a FULL 64 B L2
// granule (round-4 model: 94 us was granule-waste-bound at 32 B/64 B).
// 2 lanes per node, each 2x 16 B = 16 features. Pass dh=0 stores out0;
// pass dh=1 read-add-stores (kernel ordering = phase barrier).
// ---------------------------------------------------------------------------
static __device__ __forceinline__ void accum8(
    float wv, u32x4 u,
    float& A, float& B, float& C, float& D,
    float& E, float& F, float& G, float& H) {
    A += wv * __uint_as_float(u[0] << 16);
    B += wv * __uint_as_float(u[0] & 0xffff0000u);
    C += wv * __uint_as_float(u[1] << 16);
    D += wv * __uint_as_float(u[1] & 0xffff0000u);
    E += wv * __uint_as_float(u[2] << 16);
    F += wv * __uint_as_float(u[2] & 0xffff0000u);
    G += wv * __uint_as_float(u[3] << 16);
    H += wv * __uint_as_float(u[3] & 0xffff0000u);
}

__global__ __launch_bounds__(256) void k_aggregate(
    const uint* __restrict__ eb, const int* __restrict__ offs2,
    const ushort* __restrict__ hem, float* __restrict__ out0, const int dh) {
    const int tile8 = blockIdx.x & 7;
    const int fs = tile8 >> 1;
    const int nb = ((blockIdx.x >> 3) << 1) | (tile8 & 1);   // 0..781
    const int t = threadIdx.x;
    const int node = nb * 128 + (t >> 1);
    if (node >= NN) return;
    const int f = t & 1;                       // which 32 B half of 64 B row
    const char* hbase = reinterpret_cast<const char*>(hem)
                      + (size_t)(fs * 2 + dh) * NHALF * 64 + f * 32;
    const int beg = offs2[node * 2 + dh];
    const int end = offs2[node * 2 + dh + 1];

    float a0=0.f,a1=0.f,a2=0.f,a3=0.f,a4=0.f,a5=0.f,a6=0.f,a7=0.f;
    float a8=0.f,a9=0.f,a10=0.f,a11=0.f,a12=0.f,a13=0.f,a14=0.f,a15=0.f;

    int j = beg;
    for (; j + 2 <= end; j += 2) {
        const uint r0 = eb[j];
        const uint r1 = eb[j + 1];
        const float w0 = (float)(r0 & 0x7fffu);
        const float w1 = (float)(r1 & 0x7fffu);
        const char* p0 = hbase + ((r0 & 0xffff8000u) >> 9);
        const char* p1 = hbase + ((r1 & 0xffff8000u) >> 9);
        const u32x4 u00 = *reinterpret_cast<const u32x4*>(p0);
        const u32x4 u01 = *reinterpret_cast<const u32x4*>(p0 + 16);
        const u32x4 u10 = *reinterpret_cast<const u32x4*>(p1);
        const u32x4 u11 = *reinterpret_cast<const u32x4*>(p1 + 16);
        accum8(w0, u00, a0,a1,a2,a3,a4,a5,a6,a7);
        accum8(w0, u01, a8,a9,a10,a11,a12,a13,a14,a15);
        accum8(w1, u10, a0,a1,a2,a3,a4,a5,a6,a7);
        accum8(w1, u11, a8,a9,a10,a11,a12,a13,a14,a15);
    }
    if (j < end) {
        const uint r0 = eb[j];
        const float w0 = (float)(r0 & 0x7fffu);
        const char* p0 = hbase + ((r0 & 0xffff8000u) >> 9);
        const u32x4 u00 = *reinterpret_cast<const u32x4*>(p0);
        const u32x4 u01 = *reinterpret_cast<const u32x4*>(p0 + 16);
        accum8(w0, u00, a0,a1,a2,a3,a4,a5,a6,a7);
        accum8(w0, u01, a8,a9,a10,a11,a12,a13,a14,a15);
    }
    const float s = 1.f / 32767.f;
    float* op = out0 + (size_t)node * OUTF + fs * 32 + f * 16;
    f32x4 o0 = {a0*s, a1*s, a2*s, a3*s};
    f32x4 o1 = {a4*s, a5*s, a6*s, a7*s};
    f32x4 o2 = {a8*s, a9*s, a10*s, a11*s};
    f32x4 o3 = {a12*s, a13*s, a14*s, a15*s};
    if (dh == 0) {
        __builtin_nontemporal_store(o0, reinterpret_cast<f32x4*>(op));
        __builtin_nontemporal_store(o1, reinterpret_cast<f32x4*>(op) + 1);
        __builtin_nontemporal_store(o2, reinterpret_cast<f32x4*>(op) + 2);
        __builtin_nontemporal_store(o3, reinterpret_cast<f32x4*>(op) + 3);
    } else {
        f32x4* vp = reinterpret_cast<f32x4*>(op);
        vp[0] += o0;
        vp[1] += o1;
        vp[2] += o2;
        vp[3] += o3;
    }
}

// ---------------------------------------------------------------------------
extern "C" void kernel_launch(void* const* d_in, const int* in_sizes, int n_in,
                              void* d_out, int out_size, void* d_ws, size_t ws_size,
                              hipStream_t stream) {
    const float* x   = (const float*)d_in[0];
    const int* eidx  = (const int*)d_in[1];
    const float* W   = (const float*)d_in[2];
    const float* a   = (const float*)d_in[3];
    const float* Wem = (const float*)d_in[4];

    const int* src = eidx;
    const int* dst = eidx + NE;

    float* out0 = (float*)d_out;            // h_prime: NN*128
    float* out1 = out0 + (size_t)NN * OUTF; // edge_e: NE

    // workspace layout (~50 MB), 16B-aligned chunks
    float* wsv   = (float*)d_ws;                     // 256
    float* wdv   = wsv + 256;                        // 256
    float* s1    = wdv + 256;                        // NN
    float* s2    = s1 + NN;                          // NN
    ushort* hem  = (ushort*)(s2 + NN);               // NN*128 bf16 (tiled layout)
    ushort* Bsw  = hem + (size_t)NN * OUTF;          // 32768
    int* offs2   = (int*)(Bsw + 32768);              // 2*NN+4 (sentinel + pad)
    int* bsumB   = offs2 + 2 * NN + 4;               // NBK (pad to 784)
    int* bbase   = bsumB + 784;                      // NBK+1 (pad to 788)
    int* cntA    = bbase + 788;                      // NBA*NBK
    int* baseA   = cntA + NBA * NBK;                 // NBA*NBK
    int2* ebA    = (int2*)(baseA + NBA * NBK);       // NE * 8B
    uint* ebB    = (uint*)(ebA + NE);                // NE * 4B

    hipLaunchKernelGGL(k_setup, dim3(9), dim3(256), 0, stream,
                       W, a, Wem, wsv, wdv, Bsw);
    hipLaunchKernelGGL(k_mm, dim3((NN + 63) / 64), dim3(256), 0, stream,
                       x, Bsw, wsv, wdv, s1, s2, hem);
    hipLaunchKernelGGL(k_cnt, dim3(NBA), dim3(256), 0, stream, src, cntA);
    hipLaunchKernelGGL(k_cscan, dim3(NBK), dim3(512), 0, stream, cntA, baseA, bsumB);
    hipLaunchKernelGGL(k_bbase, dim3(1), dim3(1024), 0, stream, bsumB, bbase, offs2);
    hipLaunchKernelGGL(k_binA, dim3(NBA), dim3(256), 0, stream,
                       src, dst, s1, s2, out1, bbase, baseA, ebA);
    hipLaunchKernelGGL(k_sortB, dim3(NBK), dim3(256), 0, stream,
                       bbase, ebA, ebB, offs2);
    hipLaunchKernelGGL(k_aggregate, dim3(8 * (NBK / 2)), dim3(256), 0, stream,
                       ebB, offs2, hem, out0, 0);
    hipLaunchKernelGGL(k_aggregate, dim3(8 * (NBK / 2)), dim3(256), 0, stream,
                       ebB, offs2, hem, out0, 1);
}